// Round 3
// baseline (356.028 us; speedup 1.0000x reference)
//
#include <hip/hip_runtime.h>
#include <hip/hip_fp16.h>
#include <utility>
#include <type_traits>

// =====================================================================
// 16-qubit, batch-256 statevector simulator.
//
//  * one workgroup (1024 threads) per batch element; state = 65536 c64
//    amplitudes as fp16 (re,im) pairs.
//  * R10 STRUCTURAL CHANGE: the allocator's 64-VGPR budget is immovable
//    (R6/R9: waves_per_eu ignored; R7/R8: amdgpu_num_vgpr kills the
//    build).  Counters show ~70 MB WRITE_SIZE/dispatch = scratch spill
//    of S[64]+temps (~85 pressure vs 64 budget).  Fix: fit the budget.
//      - 48 amps (L 0..47) stay in registers,
//      - 16 amps (L 48..63, local quadrant 3) live in a thread-private
//        LDS region slds4[4][1024] (uint4 granules of 4 amps), accessed
//        via ds_read_b128/ds_write_b128, conflict-free (8 consecutive
//        lanes cover all 32 banks).
//      - coefficient regs 8 -> 4: set1 = set0 with entries 1,2 negated;
//        runtime flip f = one packed-sign XOR; compile-time role t ->
//        __hneg2 folded into v_pk_fma neg modifiers.
//    Pressure: 48 + 4 + ~8 temps + addr ~= 60-64 -> spills ~gone.
//  * CNOT rings are GF(2)-linear index maps -> virtualized (free); each
//    1q gate = pair update j <-> j^m, role parity(c & j), m/c constexpr.
//  * index layout: j = [local 6 bits][lane 6 bits][wave 4 bits]
//      - mask in local bits  -> in-register / in-granule pair update
//      - mask in lane bits   -> __shfl_xor exchange
//      - mask in wave bits   -> staged LDS chunk exchange + barriers
//
// Predicted: WRITE_SIZE 70MB -> <3MB, FETCH 37MB -> <3MB, dur 312 ->
// 170-230us, LDS_Block_Size ~133KB, bank conflicts stay low.
// =====================================================================

constexpr int NREG = 48;   // register-resident amplitudes per thread

// ---------------- compile-time GF(2) matrices ----------------
struct M16 { unsigned r[16]; };

constexpr M16 ident() { M16 m{}; for (int i = 0; i < 16; ++i) m.r[i] = 1u << i; return m; }

constexpr M16 ringm(int s) {
  M16 m = ident();
  for (int i = 15; i >= 0; --i) {
    int pc = 15 - i;
    int pt = 15 - ((i + s) & 15);
    m.r[pt] ^= m.r[pc];
  }
  return m;
}

constexpr M16 mmul(M16 A, M16 B) {
  M16 C{};
  for (int p = 0; p < 16; ++p) {
    unsigned v = 0;
    for (int q = 0; q < 16; ++q) if ((A.r[p] >> q) & 1u) v ^= B.r[q];
    C.r[p] = v;
  }
  return C;
}

constexpr M16 minv(M16 A) {
  M16 I = ident();
  for (int col = 0; col < 16; ++col) {
    int piv = -1;
    for (int row = col; row < 16; ++row) if ((A.r[row] >> col) & 1u) { piv = row; break; }
    unsigned t = A.r[piv]; A.r[piv] = A.r[col]; A.r[col] = t;
    t = I.r[piv]; I.r[piv] = I.r[col]; I.r[col] = t;
    for (int row = 0; row < 16; ++row)
      if (row != col && ((A.r[row] >> col) & 1u)) { A.r[row] ^= A.r[col]; I.r[row] ^= I.r[col]; }
  }
  return I;
}

constexpr bool meq(M16 a, M16 b) { for (int i = 0; i < 16; ++i) if (a.r[i] != b.r[i]) return false; return true; }
constexpr unsigned colmask(M16 P, int b) { unsigned m = 0; for (int p = 0; p < 16; ++p) m |= ((P.r[p] >> b) & 1u) << p; return m; }
constexpr int popc16(unsigned x) { int c = 0; for (int i = 0; i < 16; ++i) c += (x >> i) & 1; return c; }
constexpr int topbit_pow(unsigned x) { int b = 0; for (int i = 0; i < 16; ++i) if ((x >> i) & 1) b = i; return 1 << b; }

struct Tables { unsigned gm[64]; unsigned gc[64]; unsigned meas[16]; };

constexpr Tables make_tables() {
  Tables T{};
  M16 R1 = ringm(1), R2 = ringm(2);
  M16 P0 = R1;
  M16 P1 = mmul(R1, R1);
  M16 P2 = mmul(P1, R2);
  M16 P3 = mmul(P2, R2);
  M16 P[4] = { P0, P1, P2, P3 };
  for (int k = 0; k < 4; ++k) {
    M16 A = minv(P[k]);
    for (int b = 0; b < 16; ++b) {
      T.gm[k * 16 + b] = colmask(P[k], b);
      T.gc[k * 16 + b] = A.r[b];
    }
  }
  M16 A5 = minv(P[3]);
  for (int w = 0; w < 16; ++w) T.meas[w] = A5.r[15 - w];
  return T;
}

constexpr Tables TB = make_tables();

constexpr bool check_tables() {
  for (int g = 0; g < 64; ++g) if ((popc16(TB.gm[g] & TB.gc[g]) & 1) != 1) return false;
  if (!meq(mmul(ringm(1), minv(ringm(1))), ident())) return false;
  if (!meq(mmul(ringm(2), minv(ringm(2))), ident())) return false;
  return true;
}
static_assert(check_tables(), "GF(2) table inconsistency");
static_assert(sizeof(__half2) == 4, "half2 size");

// ---------------- small device helpers ----------------
template<int N, int I = 0, typename F>
__device__ __forceinline__ void sfor(F&& f) {
  if constexpr (I < N) {
    f(std::integral_constant<int, I>{});
    sfor<N, I + 1>(static_cast<F&&>(f));
  }
}

__device__ __forceinline__ int h2i(__half2 v) { return __builtin_bit_cast(int, v); }
__device__ __forceinline__ __half2 i2h(int v) { return __builtin_bit_cast(__half2, v); }
__device__ __forceinline__ unsigned h2u(__half2 v) { return __builtin_bit_cast(unsigned, v); }
__device__ __forceinline__ __half2 u2h(unsigned v) { return __builtin_bit_cast(__half2, v); }

__device__ __forceinline__ __half2 hswap(__half2 v) { __half2 r; r.x = v.y; r.y = v.x; return r; }

// y = c0*xs + (-1)^T c1*swap(xs) + (-1)^T c2*xp + c3*swap(xp)   (packed fp16)
// (runtime flip f is pre-folded into c1,c2 by the caller via sign-XOR)
template<int T>
__device__ __forceinline__ __half2 upd(__half2 xs, __half2 xp,
                                       __half2 c0, __half2 c1, __half2 c2, __half2 c3) {
  __half2 c1t = c1, c2t = c2;
  if constexpr (T) { c1t = __hneg2(c1); c2t = __hneg2(c2); }
  __half2 y = __hmul2(c0, xs);
  y = __hfma2(c1t, hswap(xs), y);
  y = __hfma2(c2t, xp, y);
  y = __hfma2(c3, hswap(xp), y);
  return y;
}

// SU(2) for U = Ry(c) Rz(b) Ry(a):  U = [[al, -conj(be)], [be, conj(al)]]
__device__ __forceinline__ void su2_coeffs(float a, float b, float c,
                                           float& are, float& aim, float& bre, float& bim) {
  float sapc, capc, samc, camc, sb, cb;
  __sincosf((a + c) * 0.5f, &sapc, &capc);
  __sincosf((a - c) * 0.5f, &samc, &camc);
  __sincosf(b * 0.5f, &sb, &cb);
  are = cb * capc;
  aim = -sb * camc;
  bre = cb * sapc;
  bim = sb * samc;
}

__device__ __forceinline__ unsigned pkh2(float lo, float hi) {
  return h2u(__floats2half2_rn(lo, hi));
}

__device__ __forceinline__ float2 cmulf(float2 a, float vr, float vi) {
  return make_float2(a.x * vr - a.y * vi, a.x * vi + a.y * vr);
}

// ---------------- LDS-resident state granules ----------------
// slds4[g][tid] holds amps L = 48 + g*4 + e (e = 0..3) packed as uint4.
// dword index = (g*1024+tid)*4 + e  ->  bank (4*tid+e)%32: 8 consecutive
// lanes cover all 32 banks -> conflict-free b128.
template<int g4>
__device__ __forceinline__ void ldg(const uint4* slds4, unsigned tid, __half2 (&a)[4]) {
  const uint4 v = slds4[g4 * 1024 + tid];
  a[0] = u2h(v.x); a[1] = u2h(v.y); a[2] = u2h(v.z); a[3] = u2h(v.w);
}
template<int g4>
__device__ __forceinline__ void stg(uint4* slds4, unsigned tid, const __half2 (&a)[4]) {
  slds4[g4 * 1024 + tid] = make_uint4(h2u(a[0]), h2u(a[1]), h2u(a[2]), h2u(a[3]));
}

// ---------------- wave-crossing chunk helpers ----------------
// chunks of 8 amps; chunks 0..5 in regs, chunks 6,7 = LDS granules {0,1},{2,3}.
template<int ch, int sb, int NR>
__device__ __forceinline__ void stage_chunk(const __half2 (&S)[NR], unsigned tid,
                                            const uint4* slds4, unsigned* xbuf) {
  if constexpr (ch < 6) {
    sfor<8>([&](auto kk) {
      constexpr int k = decltype(kk)::value;
      xbuf[(sb + k) * 1024 + tid] = h2u(S[ch * 8 + k]);
    });
  } else {
    sfor<2>([&](auto uu) {
      constexpr int u = decltype(uu)::value;
      __half2 a[4];
      ldg<(ch - 6) * 2 + u>(slds4, tid, a);
      sfor<4>([&](auto ee) {
        constexpr int e = decltype(ee)::value;
        xbuf[(sb + u * 4 + e) * 1024 + tid] = h2u(a[e]);
      });
    });
  }
}

template<int ch, int pb, unsigned mLt, unsigned ct, int NR>
__device__ __forceinline__ void compute_chunk(__half2 (&S)[NR], unsigned tid, unsigned ptid,
                                              uint4* slds4, const unsigned* xbuf,
                                              __half2 c0, __half2 c1, __half2 c2, __half2 c3) {
  if constexpr (ch < 6) {
    sfor<8>([&](auto kk) {
      constexpr int k = decltype(kk)::value;
      constexpr int L = ch * 8 + k;
      constexpr int slot = pb + ((L ^ (int)mLt) & 7);
      constexpr int t = popc16(ct & (unsigned)L) & 1;
      const __half2 xp = u2h(xbuf[slot * 1024 + ptid]);
      S[L] = upd<t>(S[L], xp, c0, c1, c2, c3);
    });
  } else {
    sfor<2>([&](auto uu) {
      constexpr int u = decltype(uu)::value;
      constexpr int g = (ch - 6) * 2 + u;
      __half2 a[4];
      ldg<g>(slds4, tid, a);
      sfor<4>([&](auto ee) {
        constexpr int e = decltype(ee)::value;
        constexpr int L = ch * 8 + u * 4 + e;
        constexpr int slot = pb + ((L ^ (int)mLt) & 7);
        constexpr int t = popc16(ct & (unsigned)L) & 1;
        const __half2 xp = u2h(xbuf[slot * 1024 + ptid]);
        a[e] = upd<t>(a[e], xp, c0, c1, c2, c3);
      });
      stg<g>(slds4, tid, a);
    });
  }
}

// ---------------- generalized gate application ----------------
// j = (tid << 6) | L;  L in [0,64): 48 reg amps + 16 LDS amps per thread.
template<int G>
__device__ __forceinline__ void apply_gate(__half2 (&S)[NREG], unsigned tid,
                                           const uint4* ctab4, uint4* slds4, unsigned* xbuf) {
  constexpr unsigned m  = TB.gm[G];
  constexpr unsigned c  = TB.gc[G];
  constexpr unsigned mL = m & 63u;    // local-bit part of pair mask
  constexpr unsigned mT = m >> 6;     // thread-bit part (lane bits 0..5, wave 6..9)
  constexpr unsigned mW = m >> 12;    // wave part
  constexpr int      dt = popc16(c & mL) & 1;  // role flip across local part

  // 4 coefficient regs; runtime flip f folded in as a packed-sign XOR.
  __half2 c0, c1, c2, c3;
  {
    const uint4 cc = ctab4[G];
    const unsigned fm = (__popc((c >> 6) & tid) & 1u) ? 0x80008000u : 0u;
    c0 = u2h(cc.x); c1 = u2h(cc.y ^ fm); c2 = u2h(cc.z ^ fm); c3 = u2h(cc.w);
  }

  constexpr unsigned dq = (mL >> 4) & 3u;  // quadrant displacement of mL
  constexpr unsigned mn = mL & 15u;        // within-quadrant part

  if constexpr (mT == 0u) {
    // ---- pure local pairs ----  (m == mL -> dt == 1)
    static_assert(dt == 1, "local pair gate must flip role");
    constexpr int hb = topbit_pow(mL);
    sfor<32>([&](auto ii) {              // reg-reg pairs
      constexpr int i  = decltype(ii)::value;
      constexpr int L0 = ((i & ~(hb - 1)) << 1) | (i & (hb - 1));
      constexpr int L1 = L0 ^ (int)mL;
      if constexpr (L0 < NREG && L1 < NREG) {
        constexpr int t = popc16(c & (unsigned)L0) & 1;
        const __half2 x0 = S[L0], x1 = S[L1];
        S[L0] = upd<t>(x0, x1, c0, c1, c2, c3);
        S[L1] = upd<t ^ dt>(x1, x0, c0, c1, c2, c3);
      }
    });
    if constexpr (dq == 0u) {
      constexpr unsigned hg = mn >> 2;   // granule displacement
      if constexpr (hg == 0u) {
        // pairs inside each granule (mn in {1,2,3})
        constexpr int eb = topbit_pow(mn);
        sfor<4>([&](auto gg4) {
          constexpr int g = decltype(gg4)::value;
          __half2 a[4]; ldg<g>(slds4, tid, a);
          sfor<2>([&](auto jj) {
            constexpr int j  = decltype(jj)::value;
            constexpr int e0 = ((j & ~(eb - 1)) << 1) | (j & (eb - 1));
            constexpr int e1 = e0 ^ (int)mn;
            constexpr int L0 = 48 + g * 4 + e0;
            constexpr int t  = popc16(c & (unsigned)L0) & 1;
            const __half2 x0 = a[e0], x1 = a[e1];
            a[e0] = upd<t>(x0, x1, c0, c1, c2, c3);
            a[e1] = upd<t ^ dt>(x1, x0, c0, c1, c2, c3);
          });
          stg<g>(slds4, tid, a);
        });
      } else {
        // granule pairs (g, g^hg)
        constexpr int gb = topbit_pow(hg);
        sfor<2>([&](auto jj) {
          constexpr int j  = decltype(jj)::value;
          constexpr int gA = ((j & ~(gb - 1)) << 1) | (j & (gb - 1));
          constexpr int gB = gA ^ (int)hg;
          __half2 a[4], bb[4];
          ldg<gA>(slds4, tid, a); ldg<gB>(slds4, tid, bb);
          sfor<4>([&](auto ee) {
            constexpr int e  = decltype(ee)::value;
            constexpr int e2 = e ^ (int)(mn & 3u);
            constexpr int L0 = 48 + gA * 4 + e;
            constexpr int t  = popc16(c & (unsigned)L0) & 1;
            const __half2 x0 = a[e], x1 = bb[e2];
            a[e]   = upd<t>(x0, x1, c0, c1, c2, c3);
            bb[e2] = upd<t ^ dt>(x1, x0, c0, c1, c2, c3);
          });
          stg<gA>(slds4, tid, a); stg<gB>(slds4, tid, bb);
        });
      }
    } else {
      // LDS quadrant pairs with reg quadrant qr = 3^dq
      constexpr int qr = 3 ^ (int)dq;
      sfor<4>([&](auto gg4) {
        constexpr int g = decltype(gg4)::value;
        __half2 a[4]; ldg<g>(slds4, tid, a);
        sfor<4>([&](auto ee) {
          constexpr int e  = decltype(ee)::value;
          constexpr int s  = g * 4 + e;
          constexpr int Lr = (qr << 4) | (s ^ (int)mn);
          static_assert(Lr < NREG, "reg partner must be register-resident");
          constexpr int tr = popc16(c & (unsigned)Lr) & 1;
          const __half2 xr = S[Lr], xl = a[e];
          S[Lr] = upd<tr>(xr, xl, c0, c1, c2, c3);
          a[e]  = upd<tr ^ dt>(xl, xr, c0, c1, c2, c3);
        });
        stg<g>(slds4, tid, a);
      });
    }
  } else if constexpr (mW == 0u) {
    // ---- lane-crossing: shfl_xor within the wave ----
    if constexpr (mL == 0u) {
      sfor<NREG>([&](auto ll) {
        constexpr int L = decltype(ll)::value;
        constexpr int t = popc16(c & (unsigned)L) & 1;
        const __half2 xp = i2h(__shfl_xor(h2i(S[L]), (int)mT, 64));
        S[L] = upd<t>(S[L], xp, c0, c1, c2, c3);
      });
      sfor<4>([&](auto gg4) {
        constexpr int g = decltype(gg4)::value;
        __half2 a[4]; ldg<g>(slds4, tid, a);
        sfor<4>([&](auto ee) {
          constexpr int e = decltype(ee)::value;
          constexpr int L = 48 + g * 4 + e;
          constexpr int t = popc16(c & (unsigned)L) & 1;
          const __half2 xp = i2h(__shfl_xor(h2i(a[e]), (int)mT, 64));
          a[e] = upd<t>(a[e], xp, c0, c1, c2, c3);
        });
        stg<g>(slds4, tid, a);
      });
    } else {
      constexpr int hb = topbit_pow(mL);
      sfor<32>([&](auto ii) {            // reg-reg pairs
        constexpr int i  = decltype(ii)::value;
        constexpr int L0 = ((i & ~(hb - 1)) << 1) | (i & (hb - 1));
        constexpr int L1 = L0 ^ (int)mL;
        if constexpr (L0 < NREG && L1 < NREG) {
          constexpr int t = popc16(c & (unsigned)L0) & 1;
          const __half2 x0 = S[L0], x1 = S[L1];
          const __half2 xp0 = i2h(__shfl_xor(h2i(x1), (int)mT, 64));
          const __half2 xp1 = i2h(__shfl_xor(h2i(x0), (int)mT, 64));
          S[L0] = upd<t>(x0, xp0, c0, c1, c2, c3);
          S[L1] = upd<t ^ dt>(x1, xp1, c0, c1, c2, c3);
        }
      });
      if constexpr (dq == 0u) {
        constexpr unsigned hg = mn >> 2;
        if constexpr (hg == 0u) {
          constexpr int eb = topbit_pow(mn);
          sfor<4>([&](auto gg4) {
            constexpr int g = decltype(gg4)::value;
            __half2 a[4]; ldg<g>(slds4, tid, a);
            sfor<2>([&](auto jj) {
              constexpr int j  = decltype(jj)::value;
              constexpr int e0 = ((j & ~(eb - 1)) << 1) | (j & (eb - 1));
              constexpr int e1 = e0 ^ (int)mn;
              constexpr int L0 = 48 + g * 4 + e0;
              constexpr int t  = popc16(c & (unsigned)L0) & 1;
              const __half2 x0 = a[e0], x1 = a[e1];
              const __half2 xp0 = i2h(__shfl_xor(h2i(x1), (int)mT, 64));
              const __half2 xp1 = i2h(__shfl_xor(h2i(x0), (int)mT, 64));
              a[e0] = upd<t>(x0, xp0, c0, c1, c2, c3);
              a[e1] = upd<t ^ dt>(x1, xp1, c0, c1, c2, c3);
            });
            stg<g>(slds4, tid, a);
          });
        } else {
          constexpr int gb = topbit_pow(hg);
          sfor<2>([&](auto jj) {
            constexpr int j  = decltype(jj)::value;
            constexpr int gA = ((j & ~(gb - 1)) << 1) | (j & (gb - 1));
            constexpr int gB = gA ^ (int)hg;
            __half2 a[4], bb[4];
            ldg<gA>(slds4, tid, a); ldg<gB>(slds4, tid, bb);
            sfor<4>([&](auto ee) {
              constexpr int e  = decltype(ee)::value;
              constexpr int e2 = e ^ (int)(mn & 3u);
              constexpr int L0 = 48 + gA * 4 + e;
              constexpr int t  = popc16(c & (unsigned)L0) & 1;
              const __half2 x0 = a[e], x1 = bb[e2];
              const __half2 xp0 = i2h(__shfl_xor(h2i(x1), (int)mT, 64));
              const __half2 xp1 = i2h(__shfl_xor(h2i(x0), (int)mT, 64));
              a[e]   = upd<t>(x0, xp0, c0, c1, c2, c3);
              bb[e2] = upd<t ^ dt>(x1, xp1, c0, c1, c2, c3);
            });
            stg<gA>(slds4, tid, a); stg<gB>(slds4, tid, bb);
          });
        }
      } else {
        constexpr int qr = 3 ^ (int)dq;
        sfor<4>([&](auto gg4) {
          constexpr int g = decltype(gg4)::value;
          __half2 a[4]; ldg<g>(slds4, tid, a);
          sfor<4>([&](auto ee) {
            constexpr int e  = decltype(ee)::value;
            constexpr int s  = g * 4 + e;
            constexpr int Lr = (qr << 4) | (s ^ (int)mn);
            static_assert(Lr < NREG, "reg partner must be register-resident");
            constexpr int tr = popc16(c & (unsigned)Lr) & 1;
            const __half2 xr = S[Lr], xl = a[e];
            const __half2 xpr = i2h(__shfl_xor(h2i(xl), (int)mT, 64)); // partner's LDS amp
            const __half2 xpl = i2h(__shfl_xor(h2i(xr), (int)mT, 64)); // partner's reg amp
            S[Lr] = upd<tr>(xr, xpr, c0, c1, c2, c3);
            a[e]  = upd<tr ^ dt>(xl, xpl, c0, c1, c2, c3);
          });
          stg<g>(slds4, tid, a);
        });
      }
    }
  } else {
    // ---- wave-crossing: staged LDS exchange through xbuf ----
    const unsigned ptid = tid ^ mT;
    constexpr unsigned hc = mL >> 3;          // chunk-xor (chunks of 8 amps)
    if constexpr (hc == 0u) {
      // partner within same 16-amp group; groups g=0..2 reg, g=3 LDS.
      sfor<4>([&](auto gg_) {
        constexpr int g = decltype(gg_)::value;
        if constexpr (g < 3) {
          sfor<16>([&](auto ss) {
            constexpr int s = decltype(ss)::value;
            xbuf[s * 1024 + tid] = h2u(S[g * 16 + s]);
          });
        } else {
          sfor<4>([&](auto grr) {
            constexpr int gr = decltype(grr)::value;
            __half2 a[4]; ldg<gr>(slds4, tid, a);
            sfor<4>([&](auto ee) {
              constexpr int e = decltype(ee)::value;
              xbuf[(gr * 4 + e) * 1024 + tid] = h2u(a[e]);
            });
          });
        }
        __syncthreads();
        if constexpr (g < 3) {
          sfor<16>([&](auto ss) {
            constexpr int s    = decltype(ss)::value;
            constexpr int L    = g * 16 + s;
            constexpr int slot = (L ^ (int)mL) & 15;
            constexpr int t    = popc16(c & (unsigned)L) & 1;
            const __half2 xp = u2h(xbuf[slot * 1024 + ptid]);
            S[L] = upd<t>(S[L], xp, c0, c1, c2, c3);
          });
        } else {
          sfor<4>([&](auto grr) {
            constexpr int gr = decltype(grr)::value;
            __half2 a[4]; ldg<gr>(slds4, tid, a);   // pre-gate values (own slot untouched)
            sfor<4>([&](auto ee) {
              constexpr int e    = decltype(ee)::value;
              constexpr int L    = 48 + gr * 4 + e;
              constexpr int slot = (L ^ (int)mL) & 15;
              constexpr int t    = popc16(c & (unsigned)L) & 1;
              const __half2 xp = u2h(xbuf[slot * 1024 + ptid]);
              a[e] = upd<t>(a[e], xp, c0, c1, c2, c3);
            });
            stg<gr>(slds4, tid, a);
          });
        }
        __syncthreads();
      });
    } else {
      // chunk pairs (cA, cB = cA^hc); chunks 6,7 are LDS granules.
      constexpr int tb = topbit_pow(hc);
      sfor<8>([&](auto cc_) {
        constexpr int cA = decltype(cc_)::value;
        if constexpr ((cA & tb) == 0) {
          constexpr int cB = cA ^ (int)hc;
          stage_chunk<cA, 0>(S, tid, slds4, xbuf);
          stage_chunk<cB, 8>(S, tid, slds4, xbuf);
          __syncthreads();
          compute_chunk<cA, 8, mL, c>(S, tid, ptid, slds4, xbuf, c0, c1, c2, c3);
          compute_chunk<cB, 0, mL, c>(S, tid, ptid, slds4, xbuf, c0, c1, c2, c3);
          __syncthreads();
        }
      });
    }
  }
}

// ---------------- main kernel ----------------
__global__ __attribute__((amdgpu_flat_work_group_size(1024, 1024),
                          amdgpu_waves_per_eu(4, 4)))
void qcir_kernel(const float* __restrict__ inputs, const float* __restrict__ weight,
                 float* __restrict__ out) {
  __shared__ uint4    slds4[4 * 1024];  // 64 KB thread-private state (L 48..63)
  __shared__ unsigned xbuf[16 * 1024];  // 64 KB exchange staging
  __shared__ uint4    ctab4[64];        // per-gate packed coeffs (c0..c3 bits)
  __shared__ float4   itab[16];         // per-wire (al, be) after enc+layer1
  __shared__ float    red[16 * 16];     // reduction scratch (wave x output)

  const unsigned tid = threadIdx.x;
  const unsigned b   = blockIdx.x;

  // ---- build coefficient tables ----
  if (tid < 64) {
    const int g = (int)tid;
    const int k = g >> 4;          // 0..3 -> layers 2..5
    const int bb = g & 15;
    const int w = 15 - bb;         // wire for this logical bit
    const int base = 48 * (k + 1) + 3 * w;
    float are, aim, bre, bim;
    su2_coeffs(weight[base], weight[base + 1], weight[base + 2], are, aim, bre, bim);
    // set0 (role 0): [c0, c1, c2, c3]; set1 = [c0, -c1, -c2, c3]
    ctab4[g] = make_uint4(pkh2(are, are), pkh2(-aim, aim),
                          pkh2(-bre, -bre), pkh2(-bim, bim));
  } else if (tid < 80) {
    const int w = (int)tid - 64;
    const float a = weight[3 * w] + inputs[b * 16 + w];  // encoding Ry fused in
    float are, aim, bre, bim;
    su2_coeffs(a, weight[3 * w + 1], weight[3 * w + 2], are, aim, bre, bim);
    itab[w] = make_float4(are, aim, bre, bim);           // U|0> = (al, be)
  }
  __syncthreads();

  // ---- init: product state after encoding + layer 1  (A1 = I) ----
  __half2 S[NREG];
  float2 P = make_float2(1.f, 0.f);
#pragma unroll
  for (int p = 6; p <= 15; ++p) {                 // thread-index bits of j
    const int bit = (int)(tid >> (p - 6)) & 1;
    const float4 t = itab[15 - p];
    P = cmulf(P, bit ? t.z : t.x, bit ? t.w : t.y);
  }
  sfor<8>([&](auto hh) {
    constexpr int h = decltype(hh)::value;        // local bits 3..5
    float2 ph = P;
    sfor<3>([&](auto qq) {
      constexpr int q   = decltype(qq)::value;    // p = 3+q
      constexpr int bit = (h >> q) & 1;
      const float4 t = itab[15 - (3 + q)];
      if constexpr (bit) ph = cmulf(ph, t.z, t.w); else ph = cmulf(ph, t.x, t.y);
    });
    if constexpr (h < 6) {
      sfor<8>([&](auto ll) {
        constexpr int l = decltype(ll)::value;    // local bits 0..2
        float2 pl = ph;
        sfor<3>([&](auto qq) {
          constexpr int q   = decltype(qq)::value;
          constexpr int bit = (l >> q) & 1;
          const float4 t = itab[15 - q];
          if constexpr (bit) pl = cmulf(pl, t.z, t.w); else pl = cmulf(pl, t.x, t.y);
        });
        S[h * 8 + l] = __floats2half2_rn(pl.x, pl.y);
      });
    } else {
      __half2 a0[4], a1[4];
      sfor<8>([&](auto ll) {
        constexpr int l = decltype(ll)::value;
        float2 pl = ph;
        sfor<3>([&](auto qq) {
          constexpr int q   = decltype(qq)::value;
          constexpr int bit = (l >> q) & 1;
          const float4 t = itab[15 - q];
          if constexpr (bit) pl = cmulf(pl, t.z, t.w); else pl = cmulf(pl, t.x, t.y);
        });
        const __half2 v = __floats2half2_rn(pl.x, pl.y);
        if constexpr (l < 4) a0[l] = v; else a1[l - 4] = v;
      });
      stg<(h - 6) * 2>(slds4, tid, a0);
      stg<(h - 6) * 2 + 1>(slds4, tid, a1);
    }
  });

  // ---- layers 2..5: 64 generalized gates (rings virtualized) ----
  sfor<64>([&](auto gg) { apply_gate<decltype(gg)::value>(S, tid, ctab4, slds4, xbuf); });

  // ---- measurement: <Z_w> via signed probability sums ----
  float acc[16];
  sfor<16>([&](auto ww) { acc[decltype(ww)::value] = 0.f; });
  sfor<NREG>([&](auto ll) {
    constexpr int L = decltype(ll)::value;
    const float re = __low2float(S[L]);
    const float im = __high2float(S[L]);
    const float p = re * re + im * im;
    sfor<16>([&](auto ww) {
      constexpr int w = decltype(ww)::value;
      constexpr int t = popc16(TB.meas[w] & 63u & (unsigned)L) & 1;
      if constexpr (t) acc[w] -= p; else acc[w] += p;
    });
  });
  sfor<4>([&](auto gg4) {
    constexpr int g = decltype(gg4)::value;
    __half2 a[4]; ldg<g>(slds4, tid, a);
    sfor<4>([&](auto ee) {
      constexpr int e = decltype(ee)::value;
      constexpr int L = 48 + g * 4 + e;
      const float re = __low2float(a[e]);
      const float im = __high2float(a[e]);
      const float p = re * re + im * im;
      sfor<16>([&](auto ww) {
        constexpr int w = decltype(ww)::value;
        constexpr int t = popc16(TB.meas[w] & 63u & (unsigned)L) & 1;
        if constexpr (t) acc[w] -= p; else acc[w] += p;
      });
    });
  });
  sfor<16>([&](auto ww) {
    constexpr int w = decltype(ww)::value;
    const unsigned fw = __popc((TB.meas[w] >> 6) & tid) & 1u;
    float z = fw ? -acc[w] : acc[w];
#pragma unroll
    for (int d = 1; d < 64; d <<= 1) z += __shfl_xor(z, d, 64);
    if ((tid & 63u) == 0u) red[(tid >> 6) * 16 + w] = z;
  });
  __syncthreads();
  if (tid < 16) {
    float s = 0.f;
#pragma unroll
    for (int v = 0; v < 16; ++v) s += red[v * 16 + tid];
    out[b * 16 + tid] = 4.f * s;
  }
}

// ---------------- launcher ----------------
extern "C" void kernel_launch(void* const* d_in, const int* in_sizes, int n_in,
                              void* d_out, int out_size, void* d_ws, size_t ws_size,
                              hipStream_t stream) {
  const float* inputs = (const float*)d_in[0];   // (B, 16) f32
  const float* weight = (const float*)d_in[1];   // (240,)  f32
  float* out = (float*)d_out;                    // (B, 16) f32
  const int B = in_sizes[0] / 16;
  qcir_kernel<<<B, 1024, 0, stream>>>(inputs, weight, out);
}